// Round 2
// baseline (1011.472 us; speedup 1.0000x reference)
//
#include <hip/hip_runtime.h>
#include <stdint.h>
#include <math.h>

// Problem constants (match reference setup_inputs)
#define NB    32768   // batch
#define NSLOT 5       // NR == NW == 5
#define DIM   512     // DR == DW
#define DK    16      // d_k

__device__ __forceinline__ uint32_t rotl32(uint32_t x, uint32_t r) {
  return (x << r) | (x >> (32u - r));
}

// Threefry-2x32, 20 rounds — bit-exact JAX implementation.
__device__ __forceinline__ void threefry2x32_20(uint32_t k0, uint32_t k1,
                                                uint32_t& x0, uint32_t& x1) {
  const uint32_t ks[3] = {k0, k1, k0 ^ k1 ^ 0x1BD11BDAu};
  const uint32_t rotA[4] = {13u, 15u, 26u, 6u};
  const uint32_t rotB[4] = {17u, 29u, 16u, 24u};
  x0 += ks[0];
  x1 += ks[1];
#pragma unroll
  for (int i = 0; i < 5; ++i) {
#pragma unroll
    for (int j = 0; j < 4; ++j) {
      uint32_t r = (i & 1) ? rotB[j] : rotA[j];
      x0 += x1;
      x1 = rotl32(x1, r);
      x1 ^= x0;
    }
    x0 += ks[(i + 1) % 3];
    x1 += ks[(i + 2) % 3] + (uint32_t)(i + 1);
  }
}

// JAX >= 0.5 default: jax_threefry_partitionable=True.
// random_bits(key,(N,)) elem i: counter = uint64(i) -> words (hi,lo)=(0,i);
// (out0,out1) = threefry2x32(key=(0,key_lo), (0,i)); 32-bit bits = out0^out1.
__device__ __forceinline__ uint32_t jax_random_bits_part(uint32_t key_lo, uint32_t i) {
  uint32_t x0 = 0u;   // hi word of 64-bit counter (i < 2^32)
  uint32_t x1 = i;    // lo word
  threefry2x32_20(0u, key_lo, x0, x1);
  return x0 ^ x1;
}

__global__ __launch_bounds__(256) void csa_kernel(
    const float* __restrict__ q,   // [NB, NSLOT, DIM]
    const float* __restrict__ kin, // [NB, NSLOT, DIM]
    const float* __restrict__ wr,  // [NSLOT, DIM, DK]
    const float* __restrict__ ww,  // [NSLOT, DIM, DK]
    float* __restrict__ out)       // [2, NB, NSLOT]
{
  const int t  = threadIdx.x;
  const int kk = t & 15;          // d_k component owned by this thread
  const int bl = t >> 4;          // local row 0..15
  const int b  = blockIdx.x * 16 + bl;

  // 7 projections: s=0,1 -> read slots 0,1 of q; s=2..6 -> write slots 0..4 of k
  float acc[7];
#pragma unroll
  for (int s = 0; s < 7; ++s) acc[s] = 0.0f;

#pragma unroll
  for (int s = 0; s < 7; ++s) {
    const float* a;
    const float* w;
    if (s < 2) {
      a = q   + ((size_t)(b * NSLOT + s)) * DIM;
      w = wr  + (size_t)s * (DIM * DK) + kk;
    } else {
      a = kin + ((size_t)(b * NSLOT + (s - 2))) * DIM;
      w = ww  + (size_t)(s - 2) * (DIM * DK) + kk;
    }
    const float4* a4 = (const float4*)a;
    float sum = 0.0f;
#pragma unroll 4
    for (int d4 = 0; d4 < DIM / 4; ++d4) {
      float4 av = a4[d4];
      const float* wd = w + (size_t)d4 * 4 * DK;
      sum = fmaf(av.x, wd[0 * DK], sum);
      sum = fmaf(av.y, wd[1 * DK], sum);
      sum = fmaf(av.z, wd[2 * DK], sum);
      sum = fmaf(av.w, wd[3 * DK], sum);
    }
    acc[s] = sum;
  }

  // scores[n][m] = dot16(read_n, write_m) / 4 — butterfly reduce over the
  // 16 lanes of this row's group (contiguous lanes within one wave).
  float score[10];
#pragma unroll
  for (int n = 0; n < 2; ++n) {
#pragma unroll
    for (int m = 0; m < NSLOT; ++m) {
      float p = acc[n] * acc[2 + m];
      p += __shfl_xor(p, 1, 16);
      p += __shfl_xor(p, 2, 16);
      p += __shfl_xor(p, 4, 16);
      p += __shfl_xor(p, 8, 16);
      score[n * NSLOT + m] = p * 0.25f;   // exact /sqrt(16)
    }
  }

  // Lanes kk==0 (key 42 / scores_1) and kk==1 (key 43 / scores_2) do the
  // gumbel argmax and write the one-hot.
  if (kk < 2) {
    const int n = kk;
    const uint32_t key_lo = (n == 0) ? 42u : 43u;
    int best = 0;
    float bestv = -INFINITY;
#pragma unroll
    for (int m = 0; m < NSLOT; ++m) {
      uint32_t i = (uint32_t)(b * NSLOT + m);
      uint32_t bits = jax_random_bits_part(key_lo, i);
      // JAX uniform: f in [0,1); u = max(1e-10f, f*(1.0f) + 1e-10f)
      float f = __uint_as_float((bits >> 9) | 0x3F800000u) - 1.0f;
      float u = fmaxf(1e-10f, f + 1e-10f);
      // gumbel: -log(-log(u)); f64 intermediates -> correctly-rounded f32
      double tt = -log((double)u);
      float g = (float)(-log(tt));
      float z = score[n * NSLOT + m] + g;   // tau == 1.0
      if (z > bestv) { bestv = z; best = m; }  // strict > : first-max tiebreak
    }
    float* o = out + (size_t)n * (NB * NSLOT) + (size_t)b * NSLOT;
#pragma unroll
    for (int m = 0; m < NSLOT; ++m) o[m] = (m == best) ? 1.0f : 0.0f;
  }
}

extern "C" void kernel_launch(void* const* d_in, const int* in_sizes, int n_in,
                              void* d_out, int out_size, void* d_ws, size_t ws_size,
                              hipStream_t stream) {
  const float* q  = (const float*)d_in[0];
  const float* k  = (const float*)d_in[1];
  const float* wr = (const float*)d_in[2];
  const float* ww = (const float*)d_in[3];
  float* out = (float*)d_out;

  dim3 grid(NB / 16);
  dim3 block(256);
  csa_kernel<<<grid, block, 0, stream>>>(q, k, wr, ww, out);
}

// Round 4
// 838.609 us; speedup vs baseline: 1.2061x; 1.2061x over previous
//
#include <hip/hip_runtime.h>
#include <stdint.h>
#include <math.h>

// Problem constants (match reference setup_inputs)
#define NB    32768   // batch
#define NSLOT 5       // NR == NW == 5
#define DIM   512     // DR == DW
#define DK    16      // d_k

__device__ __forceinline__ uint32_t rotl32(uint32_t x, uint32_t r) {
  return (x << r) | (x >> (32u - r));
}

// Threefry-2x32, 20 rounds — bit-exact JAX implementation.
__device__ __forceinline__ void threefry2x32_20(uint32_t k0, uint32_t k1,
                                                uint32_t& x0, uint32_t& x1) {
  const uint32_t ks[3] = {k0, k1, k0 ^ k1 ^ 0x1BD11BDAu};
  const uint32_t rotA[4] = {13u, 15u, 26u, 6u};
  const uint32_t rotB[4] = {17u, 29u, 16u, 24u};
  x0 += ks[0];
  x1 += ks[1];
#pragma unroll
  for (int i = 0; i < 5; ++i) {
#pragma unroll
    for (int j = 0; j < 4; ++j) {
      uint32_t r = (i & 1) ? rotB[j] : rotA[j];
      x0 += x1;
      x1 = rotl32(x1, r);
      x1 ^= x0;
    }
    x0 += ks[(i + 1) % 3];
    x1 += ks[(i + 2) % 3] + (uint32_t)(i + 1);
  }
}

// JAX (threefry_partitionable, default since 0.5): elem i of random_bits:
// (out0,out1) = threefry2x32(key=(0,key_lo), counter=(0,i)); bits = out0^out1.
__device__ __forceinline__ uint32_t jax_random_bits_part(uint32_t key_lo, uint32_t i) {
  uint32_t x0 = 0u;
  uint32_t x1 = i;
  threefry2x32_20(0u, key_lo, x0, x1);
  return x0 ^ x1;
}

// butterfly sum over the dq bits (bits 2,3 of sub)
__device__ __forceinline__ float red_dq(float v) {
  v += __shfl_xor(v, 4);
  v += __shfl_xor(v, 8);
  return v;
}

// Layout: 16 threads per row. sub = g & 15; kkq = sub & 3 (owns d_k components
// [kkq*4, kkq*4+4)); dq = sub >> 2 (owns d in [dq*128, dq*128+128)).
// Weight loads are float4 (4 components), activation loads float4 (4 d's).
__global__ __launch_bounds__(256) void csa_kernel(
    const float* __restrict__ q,   // [NB, NSLOT, DIM]
    const float* __restrict__ kin, // [NB, NSLOT, DIM]
    const float* __restrict__ wr,  // [NSLOT, DIM, DK]
    const float* __restrict__ ww,  // [NSLOT, DIM, DK]
    float* __restrict__ out)       // [2, NB, NSLOT]
{
  const int g   = blockIdx.x * 256 + threadIdx.x;
  const int sub = g & 15;
  const int row = g >> 4;
  const int kkq = sub & 3;
  const int dq  = sub >> 2;
  const int dbase = dq * 128;

  // ---- read projections: r[n][j] = sum_d q[row,n,d] * wr[n,d,kkq*4+j] ----
  float r[2][4];
#pragma unroll
  for (int n = 0; n < 2; ++n) {
    const float4* a4 = (const float4*)(q + ((size_t)row * NSLOT + n) * DIM + dbase);
    const float* wb = wr + (size_t)n * DIM * DK + (size_t)dbase * DK + kkq * 4;
    float ax = 0.f, ay = 0.f, az = 0.f, aw = 0.f;
#pragma unroll 4
    for (int it = 0; it < 32; ++it) {
      float4 av = a4[it];
      float4 w0 = *(const float4*)(wb + (size_t)(it * 4 + 0) * DK);
      float4 w1 = *(const float4*)(wb + (size_t)(it * 4 + 1) * DK);
      float4 w2 = *(const float4*)(wb + (size_t)(it * 4 + 2) * DK);
      float4 w3 = *(const float4*)(wb + (size_t)(it * 4 + 3) * DK);
      ax = fmaf(av.x, w0.x, ax); ay = fmaf(av.x, w0.y, ay);
      az = fmaf(av.x, w0.z, az); aw = fmaf(av.x, w0.w, aw);
      ax = fmaf(av.y, w1.x, ax); ay = fmaf(av.y, w1.y, ay);
      az = fmaf(av.y, w1.z, az); aw = fmaf(av.y, w1.w, aw);
      ax = fmaf(av.z, w2.x, ax); ay = fmaf(av.z, w2.y, ay);
      az = fmaf(av.z, w2.z, az); aw = fmaf(av.z, w2.w, aw);
      ax = fmaf(av.w, w3.x, ax); ay = fmaf(av.w, w3.y, ay);
      az = fmaf(av.w, w3.z, az); aw = fmaf(av.w, w3.w, aw);
    }
    r[n][0] = ax; r[n][1] = ay; r[n][2] = az; r[n][3] = aw;
  }
  // reduce over d-quarters: every lane gets full-d read comps for its kkq
#pragma unroll
  for (int n = 0; n < 2; ++n)
#pragma unroll
    for (int j = 0; j < 4; ++j) r[n][j] = red_dq(r[n][j]);

  // ---- write projections + scores, one write slot at a time ----
  float score[10];
#pragma unroll
  for (int m = 0; m < NSLOT; ++m) {
    const float4* a4 = (const float4*)(kin + ((size_t)row * NSLOT + m) * DIM + dbase);
    const float* wb = ww + (size_t)m * DIM * DK + (size_t)dbase * DK + kkq * 4;
    float ax = 0.f, ay = 0.f, az = 0.f, aw = 0.f;
#pragma unroll 4
    for (int it = 0; it < 32; ++it) {
      float4 av = a4[it];
      float4 w0 = *(const float4*)(wb + (size_t)(it * 4 + 0) * DK);
      float4 w1 = *(const float4*)(wb + (size_t)(it * 4 + 1) * DK);
      float4 w2 = *(const float4*)(wb + (size_t)(it * 4 + 2) * DK);
      float4 w3 = *(const float4*)(wb + (size_t)(it * 4 + 3) * DK);
      ax = fmaf(av.x, w0.x, ax); ay = fmaf(av.x, w0.y, ay);
      az = fmaf(av.x, w0.z, az); aw = fmaf(av.x, w0.w, aw);
      ax = fmaf(av.y, w1.x, ax); ay = fmaf(av.y, w1.y, ay);
      az = fmaf(av.y, w1.z, az); aw = fmaf(av.y, w1.w, aw);
      ax = fmaf(av.z, w2.x, ax); ay = fmaf(av.z, w2.y, ay);
      az = fmaf(av.z, w2.z, az); aw = fmaf(av.z, w2.w, aw);
      ax = fmaf(av.w, w3.x, ax); ay = fmaf(av.w, w3.y, ay);
      az = fmaf(av.w, w3.z, az); aw = fmaf(av.w, w3.w, aw);
    }
    float wc0 = red_dq(ax), wc1 = red_dq(ay), wc2 = red_dq(az), wc3 = red_dq(aw);
    // partial dot over my 4 components, then reduce over kkq lanes
    float p0 = r[0][0] * wc0 + r[0][1] * wc1 + r[0][2] * wc2 + r[0][3] * wc3;
    float p1 = r[1][0] * wc0 + r[1][1] * wc1 + r[1][2] * wc2 + r[1][3] * wc3;
    p0 += __shfl_xor(p0, 1); p0 += __shfl_xor(p0, 2);
    p1 += __shfl_xor(p1, 1); p1 += __shfl_xor(p1, 2);
    score[0 * NSLOT + m] = p0 * 0.25f;   // exact /sqrt(16)
    score[1 * NSLOT + m] = p1 * 0.25f;
  }

  // ---- gumbel argmax + one-hot (lanes sub==0 -> key 42, sub==1 -> key 43) ----
  if (sub < 2) {
    const int n = sub;
    const uint32_t key_lo = (n == 0) ? 42u : 43u;
    int best = 0;
    float bestv = -INFINITY;
#pragma unroll
    for (int m = 0; m < NSLOT; ++m) {
      uint32_t i = (uint32_t)(row * NSLOT + m);
      uint32_t bits = jax_random_bits_part(key_lo, i);
      float f = __uint_as_float((bits >> 9) | 0x3F800000u) - 1.0f;
      float u = fmaxf(1e-10f, f + 1e-10f);
      double tt = -log((double)u);
      float gmb = (float)(-log(tt));
      float z = score[n * NSLOT + m] + gmb;   // tau == 1.0
      if (z > bestv) { bestv = z; best = m; }  // first-max tiebreak
    }
    float* o = out + (size_t)n * (NB * NSLOT) + (size_t)row * NSLOT;
#pragma unroll
    for (int m = 0; m < NSLOT; ++m) o[m] = (m == best) ? 1.0f : 0.0f;
  }
}

extern "C" void kernel_launch(void* const* d_in, const int* in_sizes, int n_in,
                              void* d_out, int out_size, void* d_ws, size_t ws_size,
                              hipStream_t stream) {
  const float* q  = (const float*)d_in[0];
  const float* k  = (const float*)d_in[1];
  const float* wr = (const float*)d_in[2];
  const float* ww = (const float*)d_in[3];
  float* out = (float*)d_out;

  // 16 threads per row, 256 threads per block -> 16 rows/block
  dim3 grid(NB / 16);
  dim3 block(256);
  csa_kernel<<<grid, block, 0, stream>>>(q, k, wr, ww, out);
}